// Round 1
// 497.674 us; speedup vs baseline: 1.3620x; 1.3620x over previous
//
#include <hip/hip_runtime.h>

// AsynchronousGRUActor fused kernel — MI355X gfx950, v2.
// Restructure vs v1: (1) all weights staged once per block into XOR-swizzled
// LDS (no global weight loads in the tile loop -> no vmcnt-ordered stalls on
// MFMA operands); (2) grid-stride loop, ~8 tiles per wave, with one-tile-ahead
// register prefetch of x/hs/am so the HBM stream stays in flight behind
// counted vmcnt waits; (3) hprev via LDS f32 transpose of the prefetched hs
// rows; (4) lgkmcnt-only fences instead of __threadfence_block.

#define BB   500000
#define OBSN 128
#define HD   64
#define ADIM 16
#define NTIL (BB / 16)      // 31250 row-tiles
#define GRID 512
#define GWAV (GRID * 8)     // 4096 waves, ~7.6 tiles each

typedef __attribute__((ext_vector_type(8))) short short8;
typedef __attribute__((ext_vector_type(4))) float f32x4;

__device__ __forceinline__ unsigned short f2b(float f) {
  union { float f; unsigned u; } c; c.f = f;
  return (unsigned short)((c.u + 0x7fffu + ((c.u >> 16) & 1u)) >> 16);  // RNE
}
__device__ __forceinline__ unsigned pk2(float a, float b) {
  return (unsigned)f2b(a) | ((unsigned)f2b(b) << 16);
}
__device__ __forceinline__ short8 cvt_frag(float4 a, float4 b) {
  union { short8 v; unsigned u[4]; } t;
  t.u[0] = pk2(a.x, a.y); t.u[1] = pk2(a.z, a.w);
  t.u[2] = pk2(b.x, b.y); t.u[3] = pk2(b.z, b.w);
  return t.v;
}
__device__ __forceinline__ float fsigmoid(float x) {
  return __builtin_amdgcn_rcpf(1.f + __builtin_amdgcn_exp2f(-1.44269504f * x));
}
__device__ __forceinline__ float ftanh(float x) {
  return 1.f - 2.f * __builtin_amdgcn_rcpf(1.f + __builtin_amdgcn_exp2f(2.88539008f * x));
}

// d_ws layout (ushort), PRE-SWIZZLED within each row: position [n][k'] holds
// source element [n][k' ^ ((n&7)<<3)].  Regions: W1[64][128] @0 |
// WRZ[128][128] @8192 | WIN[64][64] @24576 | WHN[64][64] @28672 | W2[16][64] @32768.
__global__ void convert_weights(const float* __restrict__ fc1_w,
                                const float* __restrict__ w_ih,
                                const float* __restrict__ w_hh,
                                const float* __restrict__ fc2_w,
                                unsigned short* __restrict__ ws) {
  int i = blockIdx.x * 256 + threadIdx.x;
  if (i < 8192) {
    int n = i >> 7, k = (i & 127) ^ ((n & 7) << 3);
    ws[i] = f2b(fc1_w[n * 128 + k]);
  } else if (i < 24576) {
    int j = i - 8192, n = j >> 7, k = (j & 127) ^ ((n & 7) << 3);
    float v = (k < 64) ? w_ih[n * 64 + k] : w_hh[n * 64 + (k - 64)];
    ws[i] = f2b(v);
  } else if (i < 28672) {
    int j = i - 24576, n = j >> 6, k = (j & 63) ^ ((n & 7) << 3);
    ws[i] = f2b(w_ih[8192 + n * 64 + k]);
  } else if (i < 32768) {
    int j = i - 28672, n = j >> 6, k = (j & 63) ^ ((n & 7) << 3);
    ws[i] = f2b(w_hh[8192 + n * 64 + k]);
  } else if (i < 33792) {
    int j = i - 32768, n = j >> 6, k = (j & 63) ^ ((n & 7) << 3);
    ws[i] = f2b(fc2_w[n * 64 + k]);
  }
}

struct Batch {        // one tile's prefetched stream: 13 VMEM loads, 52 VGPRs
  float4 x[8];        // 16 rows x 128 cols of x (this lane's fragment rows)
  float4 h[4];        // 16 rows x 64 cols of hidden_states
  int4   am4;         // active_masks for this lane's 4 output rows
};

#define LDS_FENCE() asm volatile("s_waitcnt lgkmcnt(0)" ::: "memory")

__global__ __launch_bounds__(512) void gru_actor_main(
    const float* __restrict__ x, const float* __restrict__ hs,
    const int* __restrict__ am,
    const float* __restrict__ fc1_b, const float* __restrict__ b_ih,
    const float* __restrict__ b_hh, const float* __restrict__ fc2_b,
    const unsigned short* __restrict__ wb, float* __restrict__ out) {
  __shared__ __align__(16) unsigned short lw[33792];       // all weights, swizzled (66 KB)
  __shared__ __align__(16) unsigned short sb_all[8][16 * 72]; // per-wave bf16 scratch
  __shared__ __align__(16) float hf_all[8][16 * 68];       // per-wave hs f32 transpose

  const int tid = threadIdx.x;
#pragma unroll
  for (int i = 0; i < 9; ++i) {       // linear 16B copy: 33792 ushorts = 4224 chunks
    int c = tid + i * 512;
    if (c < 4224) ((short8*)lw)[c] = ((const short8*)wb)[c];
  }
  __syncthreads();                    // only barrier in the kernel

  const int wv = tid >> 6, lane = tid & 63;
  const int col = lane & 15, quad = lane >> 4;
  const int sw = (col & 7) << 3;      // row&7 == col&7 for every weight row we touch
  unsigned short* sb = sb_all[wv];
  float* hf = hf_all[wv];

  // Tile-invariant biases, hoisted out of the loop (no global loads inside it).
  float b1v[4], brv[4], bzv[4], biv[4], bhv[4];
#pragma unroll
  for (int nt = 0; nt < 4; ++nt) {
    int c = nt * 16 + col;
    b1v[nt] = fc1_b[c];
    brv[nt] = b_ih[c] + b_hh[c];
    bzv[nt] = b_ih[64 + c] + b_hh[64 + c];
    biv[nt] = b_ih[128 + c];
    bhv[nt] = b_hh[128 + c];
  }
  const float b2 = fc2_b[col];
  const f32x4 zero4 = {0.f, 0.f, 0.f, 0.f};

  auto prefetch = [&](Batch& b, int t) {
    const int r0 = t * 16;
    const float* xp = x + (r0 + col) * OBSN + quad * 8;
#pragma unroll
    for (int kt = 0; kt < 4; ++kt) {
      b.x[2 * kt]     = *(const float4*)(xp + kt * 32);
      b.x[2 * kt + 1] = *(const float4*)(xp + kt * 32 + 4);
    }
    const float* hp = hs + (r0 + col) * HD + quad * 8;
#pragma unroll
    for (int kt = 0; kt < 2; ++kt) {
      b.h[2 * kt]     = *(const float4*)(hp + kt * 32);
      b.h[2 * kt + 1] = *(const float4*)(hp + kt * 32 + 4);
    }
    b.am4 = *(const int4*)(am + r0 + quad * 4);
  };

  auto process = [&](const Batch& bt, int t) {
    const int r0 = t * 16;
    // Stash hs rows (f32) for the gate phase's hprev (cross-lane transpose).
#pragma unroll
    for (int kt = 0; kt < 2; ++kt) {
      *(float4*)(hf + col * 68 + kt * 32 + quad * 8)     = bt.h[2 * kt];
      *(float4*)(hf + col * 68 + kt * 32 + quad * 8 + 4) = bt.h[2 * kt + 1];
    }
    // ---- Phase 1: a = tanh(x @ fc1_w^T + fc1_b) -> sb (bf16) ----
    f32x4 accA[4] = {zero4, zero4, zero4, zero4};
#pragma unroll
    for (int kt = 0; kt < 4; ++kt) {
      short8 af = cvt_frag(bt.x[2 * kt], bt.x[2 * kt + 1]);
#pragma unroll
      for (int nt = 0; nt < 4; ++nt) {
        short8 bf = *(const short8*)(lw + (nt * 16 + col) * 128 + ((kt * 32 + quad * 8) ^ sw));
        accA[nt] = __builtin_amdgcn_mfma_f32_16x16x32_bf16(af, bf, accA[nt], 0, 0, 0);
      }
    }
#pragma unroll
    for (int nt = 0; nt < 4; ++nt) {
#pragma unroll
      for (int rg = 0; rg < 4; ++rg) {
        float a = ftanh(accA[nt][rg] + b1v[nt]);
        sb[(quad * 4 + rg) * 72 + nt * 16 + col] = f2b(a);
      }
    }
    LDS_FENCE();
    // ---- Phase 2: rz = [a,h] @ WRZ^T ; i_n = a @ WIN^T ; h_n = h @ WHN^T ----
    f32x4 rz[8]  = {zero4, zero4, zero4, zero4, zero4, zero4, zero4, zero4};
    f32x4 gin[4] = {zero4, zero4, zero4, zero4};
    f32x4 ghn[4] = {zero4, zero4, zero4, zero4};
#pragma unroll
    for (int kt = 0; kt < 2; ++kt) {  // K 0..63 : a
      short8 af = *(const short8*)(sb + col * 72 + kt * 32 + quad * 8);
#pragma unroll
      for (int nt = 0; nt < 8; ++nt) {
        short8 bf = *(const short8*)(lw + 8192 + (nt * 16 + col) * 128 + ((kt * 32 + quad * 8) ^ sw));
        rz[nt] = __builtin_amdgcn_mfma_f32_16x16x32_bf16(af, bf, rz[nt], 0, 0, 0);
      }
#pragma unroll
      for (int nt = 0; nt < 4; ++nt) {
        short8 bf = *(const short8*)(lw + 24576 + (nt * 16 + col) * 64 + ((kt * 32 + quad * 8) ^ sw));
        gin[nt] = __builtin_amdgcn_mfma_f32_16x16x32_bf16(af, bf, gin[nt], 0, 0, 0);
      }
    }
#pragma unroll
    for (int kt = 0; kt < 2; ++kt) {  // K 64..127 : h
      short8 af = cvt_frag(bt.h[2 * kt], bt.h[2 * kt + 1]);
#pragma unroll
      for (int nt = 0; nt < 8; ++nt) {
        short8 bf = *(const short8*)(lw + 8192 + (nt * 16 + col) * 128 + 64 + ((kt * 32 + quad * 8) ^ sw));
        rz[nt] = __builtin_amdgcn_mfma_f32_16x16x32_bf16(af, bf, rz[nt], 0, 0, 0);
      }
#pragma unroll
      for (int nt = 0; nt < 4; ++nt) {
        short8 bf = *(const short8*)(lw + 28672 + (nt * 16 + col) * 64 + ((kt * 32 + quad * 8) ^ sw));
        ghn[nt] = __builtin_amdgcn_mfma_f32_16x16x32_bf16(af, bf, ghn[nt], 0, 0, 0);
      }
    }
    // ---- Gates + masked update; h_new -> global + sb ----
    const int rowbase = r0 + quad * 4;
    const int amr[4] = {bt.am4.x, bt.am4.y, bt.am4.z, bt.am4.w};
#pragma unroll
    for (int nt = 0; nt < 4; ++nt) {
#pragma unroll
      for (int rg = 0; rg < 4; ++rg) {
        float r = fsigmoid(rz[nt][rg] + brv[nt]);
        float z = fsigmoid(rz[nt + 4][rg] + bzv[nt]);
        float n = ftanh(gin[nt][rg] + biv[nt] + r * (ghn[nt][rg] + bhv[nt]));
        float hprev = hf[(quad * 4 + rg) * 68 + nt * 16 + col];
        float hu = (1.f - z) * n + z * hprev;
        float hne = (amr[rg] != 0) ? hu : hprev;
        out[(size_t)BB * ADIM + (size_t)(rowbase + rg) * HD + nt * 16 + col] = hne;
        sb[(quad * 4 + rg) * 72 + nt * 16 + col] = f2b(hne);
      }
    }
    LDS_FENCE();
    // ---- Phase 3: logits = h_new @ fc2_w^T + fc2_b ----
    f32x4 acc2 = zero4;
#pragma unroll
    for (int kt = 0; kt < 2; ++kt) {
      short8 af = *(const short8*)(sb + col * 72 + kt * 32 + quad * 8);
      short8 bf = *(const short8*)(lw + 32768 + col * 64 + ((kt * 32 + quad * 8) ^ sw));
      acc2 = __builtin_amdgcn_mfma_f32_16x16x32_bf16(af, bf, acc2, 0, 0, 0);
    }
#pragma unroll
    for (int rg = 0; rg < 4; ++rg)
      out[(size_t)(rowbase + rg) * ADIM + col] = acc2[rg] + b2;
  };

  // Grid-stride tile loop, two-body unrolled for register double-buffering.
  // Prefetch is UNCONDITIONAL (self-tile dummy on the last iteration) so the
  // outstanding-VMEM count is path-independent and the compiler's counted
  // vmcnt waits never drain the next tile's stream.
  int t = blockIdx.x * 8 + wv;
  if (t >= NTIL) return;
  Batch A, B;
  prefetch(A, t);
  for (;;) {
    int tn = t + GWAV;
    prefetch(B, (tn < NTIL) ? tn : t);
    __builtin_amdgcn_sched_barrier(0);   // pin prefetch issue above the compute
    process(A, t);
    if (tn >= NTIL) break;
    t = tn;
    tn = t + GWAV;
    prefetch(A, (tn < NTIL) ? tn : t);
    __builtin_amdgcn_sched_barrier(0);
    process(B, t);
    if (tn >= NTIL) break;
    t = tn;
  }
}

extern "C" void kernel_launch(void* const* d_in, const int* in_sizes, int n_in,
                              void* d_out, int out_size, void* d_ws, size_t ws_size,
                              hipStream_t stream) {
  const float* x     = (const float*)d_in[0];
  const float* hsp   = (const float*)d_in[1];
  const int*   amp   = (const int*)d_in[2];
  const float* fc1_w = (const float*)d_in[3];
  const float* fc1_b = (const float*)d_in[4];
  const float* w_ih  = (const float*)d_in[5];
  const float* w_hh  = (const float*)d_in[6];
  const float* b_ih  = (const float*)d_in[7];
  const float* b_hh  = (const float*)d_in[8];
  const float* fc2_w = (const float*)d_in[9];
  const float* fc2_b = (const float*)d_in[10];
  unsigned short* wb = (unsigned short*)d_ws;
  float* out = (float*)d_out;

  convert_weights<<<dim3(132), dim3(256), 0, stream>>>(fc1_w, w_ih, w_hh, fc2_w, wb);
  gru_actor_main<<<dim3(GRID), dim3(512), 0, stream>>>(
      x, hsp, amp, fc1_b, b_ih, b_hh, fc2_b, wb, out);
}